// Round 10
// baseline (274.360 us; speedup 1.0000x reference)
//
#include <hip/hip_runtime.h>
#include <cstdint>
#include <cstddef>

#define IN_C  512
#define OUT_C 1024
#define NSAMP 8192
#define KTOT  1536

typedef __bf16 bf16x8 __attribute__((ext_vector_type(8)));
typedef float  f32x16 __attribute__((ext_vector_type(16)));

#define SBAR()   __builtin_amdgcn_s_barrier()
#define SFENCE() __builtin_amdgcn_sched_barrier(0)
#define VM4()    asm volatile("s_waitcnt vmcnt(4)")
#define VM0()    asm volatile("s_waitcnt vmcnt(0)")

__device__ __forceinline__ unsigned short f2bf(float f) {
    unsigned int u = __float_as_uint(f);
    u += 0x7FFFu + ((u >> 16) & 1u);   // round-to-nearest-even
    return (unsigned short)(u >> 16);
}
__device__ __forceinline__ float sigmoid_f(float x) { return 1.0f / (1.0f + __expf(-x)); }
__device__ __forceinline__ float tanh_f(float x) {
    float e = __expf(2.0f * x);
    return 1.0f - 2.0f / (e + 1.0f);
}

// ---- transpose + f32->bf16: in (R x C) row-major -> out (C x R) row-major ----
__global__ void tcvt_kernel(const float* __restrict__ in, unsigned short* __restrict__ out,
                            int R, int C) {
    __shared__ float t[32][33];
    const int tx = threadIdx.x, ty = threadIdx.y;
    const int c0 = blockIdx.x * 32, r0 = blockIdx.y * 32;
#pragma unroll
    for (int i = 0; i < 4; ++i)
        t[ty + i * 8][tx] = in[(size_t)(r0 + ty + i * 8) * C + (c0 + tx)];
    __syncthreads();
#pragma unroll
    for (int i = 0; i < 4; ++i)
        out[(size_t)(c0 + ty + i * 8) * R + (r0 + tx)] = f2bf(t[tx][ty + i * 8]);
}

// ---- pack A'[4096][1536]: row m = out_row*4 + gate; k<512 from wx_g, else wh_g ----
__global__ void packA_kernel(const float* __restrict__ x0, const float* __restrict__ x1,
                             const float* __restrict__ x2, const float* __restrict__ x3,
                             const float* __restrict__ h0, const float* __restrict__ h1,
                             const float* __restrict__ h2, const float* __restrict__ h3,
                             unsigned short* __restrict__ Ap) {
    const int idx = blockIdx.x * 256 + threadIdx.x;   // 4096*192 total (8 k each)
    const int m = idx / 192, k8 = idx % 192;
    const int g = m & 3, r = m >> 2;
    const float* src;
    if (k8 < 64) {
        const float* a = (g & 2) ? ((g & 1) ? x3 : x2) : ((g & 1) ? x1 : x0);
        src = a + (size_t)r * IN_C + k8 * 8;
    } else {
        const float* a = (g & 2) ? ((g & 1) ? h3 : h2) : ((g & 1) ? h1 : h0);
        src = a + (size_t)r * OUT_C + (k8 - 64) * 8;
    }
    float4 v0 = reinterpret_cast<const float4*>(src)[0];
    float4 v1 = reinterpret_cast<const float4*>(src)[1];
    ushort4 o0, o1;
    o0.x = f2bf(v0.x); o0.y = f2bf(v0.y); o0.z = f2bf(v0.z); o0.w = f2bf(v0.w);
    o1.x = f2bf(v1.x); o1.y = f2bf(v1.y); o1.z = f2bf(v1.z); o1.w = f2bf(v1.w);
    ushort4* dst = reinterpret_cast<ushort4*>(Ap + (size_t)m * KTOT + k8 * 8);
    dst[0] = o0; dst[1] = o1;
}

// ---- fused MDLSTM as one 256x256-tile GEMM, 8 waves, 32x32x16 MFMA.
// m201-style phases: {ds_reads | stage | BAR | 16 MFMA | BAR}, 2 phases/K-tile,
// counted vmcnt(4) once per tile. Per-wave 128x64 out as 4x2 32x32 acc tiles.
__global__ __launch_bounds__(512, 2) void mdlstm_main(
    const unsigned short* __restrict__ Ap,    // [4096][1536] bf16
    const unsigned short* __restrict__ xT,    // [8192][512]  bf16
    const unsigned short* __restrict__ h0T,   // [8192][1024] bf16
    const unsigned short* __restrict__ h1T,   // [8192][1024] bf16
    const float* __restrict__ b_i, const float* __restrict__ b_f,
    const float* __restrict__ b_g, const float* __restrict__ b_o,
    const float* __restrict__ cp0, const float* __restrict__ cp1,
    const float* __restrict__ wsum,
    float* __restrict__ out)
{
    // 2 bufs x 64KB: A(half0)@0, A(half1)@16K, B(dir0)@32K, B(dir1)@48K
    // each 16KB region = [kk(2)][row(128)][64B], byte-swizzle ((row>>1)&3)<<4
    __shared__ __align__(16) unsigned char smem[131072];

    const int tid  = threadIdx.x;
    const int lane = tid & 63;
    const int wid  = tid >> 6;      // 0..7
    const int wm   = wid >> 2;      // 0..1 : A-half (128 rows)
    const int wn   = wid & 3;       // 0..3 : (dir = wn>>1, sample-half = wn&1)
    const int l31  = lane & 31;
    const int h32  = lane >> 5;     // 0..1

    const int by    = blockIdx.y;         // 0..15
    const int bcol  = blockIdx.x * 128;   // sample base
    const int browM = by * 256;           // A'-row base

    f32x16 acc[4][2];
#pragma unroll
    for (int mb = 0; mb < 4; ++mb)
#pragma unroll
        for (int nb = 0; nb < 2; ++nb)
#pragma unroll
            for (int r = 0; r < 16; ++r)
                acc[mb][nb][r] = 0.f;

    auto stage_A = [&](int P, int hA, int j1) {
#pragma unroll
        for (int c = 0; c < 2; ++c) {
            const int u    = c * 8192 + tid * 16;
            const int rloc = (u >> 6) & 127;
            const int kb   = (u & 63) ^ (((u >> 7) & 3) << 4);
            const char* src = (const char*)Ap
                + ((size_t)(browM + hA * 128 + rloc) * KTOT + j1 * 64 + c * 32) * 2 + kb;
            __builtin_amdgcn_global_load_lds((const unsigned int*)src,
                (unsigned int*)(smem + P * 65536 + hA * 16384 + u), 16, 0, 0);
        }
    };
    auto stage_B = [&](int P, int d, int j2) {
#pragma unroll
        for (int c = 0; c < 2; ++c) {
            const int u    = c * 8192 + tid * 16;
            const int rloc = (u >> 6) & 127;
            const int kb   = (u & 63) ^ (((u >> 7) & 3) << 4);
            const char* src;
            if (j2 < 8) {   // x-region: both dirs read the same xT tile
                src = (const char*)xT + ((size_t)(bcol + rloc) * IN_C + j2 * 64 + c * 32) * 2 + kb;
            } else {
                const unsigned short* hsrc = d ? h1T : h0T;
                src = (const char*)hsrc + ((size_t)(bcol + rloc) * OUT_C + (j2 - 8) * 64 + c * 32) * 2 + kb;
            }
            __builtin_amdgcn_global_load_lds((const unsigned int*)src,
                (unsigned int*)(smem + P * 65536 + 32768 + d * 16384 + u), 16, 0, 0);
        }
    };

    // fragment: lane l supplies row (l&31), k-run of 8 at slice s: k=(l>>5)*8+s*16
    auto fragA = [&](int P, int mb, int s) -> bf16x8 {
        const int rloc = mb * 32 + l31;                    // within wm's 128-row half
        const int u = (s >> 1) * 8192 + rloc * 64
                    + (((s & 1) * 32 + h32 * 16) ^ (((rloc >> 1) & 3) << 4));
        return *reinterpret_cast<const bf16x8*>(smem + P * 65536 + wm * 16384 + u);
    };
    auto fragB = [&](int P, int nb, int s) -> bf16x8 {
        const int rloc = (wn & 1) * 64 + nb * 32 + l31;    // within dir's 128-row region
        const int u = (s >> 1) * 8192 + rloc * 64
                    + (((s & 1) * 32 + h32 * 16) ^ (((rloc >> 1) & 3) << 4));
        return *reinterpret_cast<const bf16x8*>(smem + P * 65536 + 32768 + (wn >> 1) * 16384 + u);
    };

    auto ktile = [&](int j, int P, int PN) {
        const bool stA = (j < 23), stB = (j < 22);
        bf16x8 aF[2][4], bF[2][4];

        // ---- ph1: reads (8 bF + 8 aF) | stage A(j+1) | BAR | MFMA mb0,1 | BAR ----
#pragma unroll
        for (int nb = 0; nb < 2; ++nb)
#pragma unroll
            for (int s = 0; s < 4; ++s) bF[nb][s] = fragB(P, nb, s);
#pragma unroll
        for (int mb = 0; mb < 2; ++mb)
#pragma unroll
            for (int s = 0; s < 4; ++s) aF[mb][s] = fragA(P, mb, s);
        if (stA) { stage_A(PN, 0, j + 1); stage_A(PN, 1, j + 1); }
        SBAR();
        __builtin_amdgcn_s_setprio(1);
#pragma unroll
        for (int s = 0; s < 4; ++s)
#pragma unroll
            for (int mb = 0; mb < 2; ++mb)
#pragma unroll
                for (int nb = 0; nb < 2; ++nb)
                    acc[mb][nb] = __builtin_amdgcn_mfma_f32_32x32x16_bf16(
                        aF[mb][s], bF[nb][s], acc[mb][nb], 0, 0, 0);
        __builtin_amdgcn_s_setprio(0);
        SBAR();

        // ---- ph2: reads (8 aF for mb2,3) | stage B(j+2) | BAR | MFMA mb2,3 | vmcnt | BAR ----
#pragma unroll
        for (int mb = 0; mb < 2; ++mb)
#pragma unroll
            for (int s = 0; s < 4; ++s) aF[mb][s] = fragA(P, mb + 2, s);
        if (stB) { stage_B(P, 0, j + 2); stage_B(P, 1, j + 2); }
        SBAR();
        __builtin_amdgcn_s_setprio(1);
#pragma unroll
        for (int s = 0; s < 4; ++s)
#pragma unroll
            for (int mb = 0; mb < 2; ++mb)
#pragma unroll
                for (int nb = 0; nb < 2; ++nb)
                    acc[mb + 2][nb] = __builtin_amdgcn_mfma_f32_32x32x16_bf16(
                        aF[mb][s], bF[nb][s], acc[mb + 2][nb], 0, 0, 0);
        __builtin_amdgcn_s_setprio(0);
        if (j < 22)       { SFENCE(); VM4(); SFENCE(); }
        else if (j == 22) { SFENCE(); VM0(); SFENCE(); }
        SBAR();
    };

    // ---------------- prologue: A(0), B(0), B(1) ----------------
    stage_A(0, 0, 0); stage_A(0, 1, 0);
    stage_B(0, 0, 0); stage_B(0, 1, 0);
    stage_B(1, 0, 1); stage_B(1, 1, 1);
    SFENCE(); VM4(); SFENCE();            // A(0),B(0) landed; B(1) may fly
    SBAR();

    // ---------------- main loop: 24 K-tiles ----------------
#pragma unroll 1
    for (int jj = 0; jj < 12; ++jj) {
        ktile(2 * jj,     0, 1);
        ktile(2 * jj + 1, 1, 0);
    }

    // ---------------- epilogue: lane-local gates; LDS exchange for dir combine ----
    // C/D 32x32 layout: reg r=4q+g -> gate g, row 8q+4h+g; col = lane&31
    const int   d  = wn >> 1;
    const float* cp = d ? cp1 : cp0;
    const float wd  = wsum[d];

    float rc[4][2][4], rh[4][2][4];
#pragma unroll
    for (int mb = 0; mb < 4; ++mb)
#pragma unroll
        for (int nb = 0; nb < 2; ++nb)
#pragma unroll
            for (int q = 0; q < 4; ++q) {
                const int orow = by * 64 + wm * 32 + mb * 8 + 2 * q + h32;
                const int scol = bcol + (wn & 1) * 64 + nb * 32 + l31;
                float i_ = sigmoid_f(acc[mb][nb][4 * q + 0] + b_i[orow]);
                float f_ = sigmoid_f(acc[mb][nb][4 * q + 1] + b_f[orow]);
                float g_ = tanh_f  (acc[mb][nb][4 * q + 2] + b_g[orow]);
                float o_ = sigmoid_f(acc[mb][nb][4 * q + 3] + b_o[orow]);
                float cc = f_ * cp[(size_t)orow * NSAMP + scol] + i_ * g_;
                float hh = o_ * tanh_f(cc);
                rc[mb][nb][q] = wd * cc;
                rh[mb][nb][q] = wd * hh;
            }

    float* ex = (float*)smem;
    const int rbase = (wm * 2 + (wn & 1)) * 4096;   // 16KB region per (wm, sample-half)
    if (d == 1) {
#pragma unroll
        for (int mb = 0; mb < 4; ++mb)
#pragma unroll
            for (int nb = 0; nb < 2; ++nb)
#pragma unroll
                for (int q = 0; q < 4; ++q) {
                    const int slot = rbase + ((mb * 2 + nb) * 4 + q) * 64 + lane;
                    ex[slot]        = rc[mb][nb][q];
                    ex[slot + 2048] = rh[mb][nb][q];
                }
    }
    SBAR();
    if (d == 0) {
#pragma unroll
        for (int mb = 0; mb < 4; ++mb)
#pragma unroll
            for (int nb = 0; nb < 2; ++nb)
#pragma unroll
                for (int q = 0; q < 4; ++q) {
                    const int orow = by * 64 + wm * 32 + mb * 8 + 2 * q + h32;
                    const int scol = bcol + (wn & 1) * 64 + nb * 32 + l31;
                    const int slot = rbase + ((mb * 2 + nb) * 4 + q) * 64 + lane;
                    out[(size_t)orow * NSAMP + scol] = rc[mb][nb][q] + ex[slot];
                    out[(size_t)OUT_C * NSAMP + (size_t)orow * NSAMP + scol]
                        = rh[mb][nb][q] + ex[slot + 2048];
                }
    }
}

extern "C" void kernel_launch(void* const* d_in, const int* in_sizes, int n_in,
                              void* d_out, int out_size, void* d_ws, size_t ws_size,
                              hipStream_t stream) {
    (void)in_sizes; (void)n_in; (void)out_size; (void)ws_size;

    const float* x    = (const float*)d_in[0];
    const float* cp0  = (const float*)d_in[1];
    const float* hp0  = (const float*)d_in[2];
    const float* cp1  = (const float*)d_in[3];
    const float* hp1  = (const float*)d_in[4];
    const float* b_i  = (const float*)d_in[13];
    const float* b_f  = (const float*)d_in[14];
    const float* b_g  = (const float*)d_in[15];
    const float* b_o  = (const float*)d_in[16];
    const float* wsum = (const float*)d_in[17];
    float* out = (float*)d_out;

    // workspace: xT 8MB @0, h0T 16MB @8M, h1T 16MB @24M, Ap 12MB @40M
    char* ws = (char*)d_ws;
    unsigned short* xT  = (unsigned short*)(ws);
    unsigned short* h0T = (unsigned short*)(ws + (size_t)8  * 1024 * 1024);
    unsigned short* h1T = (unsigned short*)(ws + (size_t)24 * 1024 * 1024);
    unsigned short* Ap  = (unsigned short*)(ws + (size_t)40 * 1024 * 1024);

    dim3 tb(32, 8);
    tcvt_kernel<<<dim3(NSAMP / 32, IN_C  / 32), tb, 0, stream>>>(x,   xT,  IN_C,  NSAMP);
    tcvt_kernel<<<dim3(NSAMP / 32, OUT_C / 32), tb, 0, stream>>>(hp0, h0T, OUT_C, NSAMP);
    tcvt_kernel<<<dim3(NSAMP / 32, OUT_C / 32), tb, 0, stream>>>(hp1, h1T, OUT_C, NSAMP);

    packA_kernel<<<(4096 * 192) / 256, 256, 0, stream>>>(
        (const float*)d_in[5], (const float*)d_in[6], (const float*)d_in[7], (const float*)d_in[8],
        (const float*)d_in[9], (const float*)d_in[10], (const float*)d_in[11], (const float*)d_in[12],
        Ap);

    mdlstm_main<<<dim3(NSAMP / 128, OUT_C / 64), 512, 0, stream>>>(
        Ap, xT, h0T, h1T, b_i, b_f, b_g, b_o, cp0, cp1, wsum, out);
}

// Round 12
// 237.997 us; speedup vs baseline: 1.1528x; 1.1528x over previous
//
#include <hip/hip_runtime.h>
#include <cstdint>
#include <cstddef>

#define IN_C  512
#define OUT_C 1024
#define NSAMP 8192
#define KTOT  1536

typedef __bf16 bf16x8 __attribute__((ext_vector_type(8)));
typedef float  f32x4  __attribute__((ext_vector_type(4)));

#define SBAR()   __builtin_amdgcn_s_barrier()
#define SFENCE() __builtin_amdgcn_sched_barrier(0)
#define VM0()    asm volatile("s_waitcnt vmcnt(0)")

__device__ __forceinline__ unsigned short f2bf(float f) {
    unsigned int u = __float_as_uint(f);
    u += 0x7FFFu + ((u >> 16) & 1u);   // round-to-nearest-even
    return (unsigned short)(u >> 16);
}
__device__ __forceinline__ float sigmoid_f(float x) { return 1.0f / (1.0f + __expf(-x)); }
__device__ __forceinline__ float tanh_f(float x) {
    float e = __expf(2.0f * x);
    return 1.0f - 2.0f / (e + 1.0f);
}

// ---- transpose + f32->bf16: in (R x C) row-major -> out (C x R) row-major ----
__global__ void tcvt_kernel(const float* __restrict__ in, unsigned short* __restrict__ out,
                            int R, int C) {
    __shared__ float t[32][33];
    const int tx = threadIdx.x, ty = threadIdx.y;
    const int c0 = blockIdx.x * 32, r0 = blockIdx.y * 32;
#pragma unroll
    for (int i = 0; i < 4; ++i)
        t[ty + i * 8][tx] = in[(size_t)(r0 + ty + i * 8) * C + (c0 + tx)];
    __syncthreads();
#pragma unroll
    for (int i = 0; i < 4; ++i)
        out[(size_t)(c0 + ty + i * 8) * R + (r0 + tx)] = f2bf(t[tx][ty + i * 8]);
}

// ---- pack A'[4096][1536]: row m = out_row*4 + gate; k<512 from wx_g, else wh_g ----
__global__ void packA_kernel(const float* __restrict__ x0, const float* __restrict__ x1,
                             const float* __restrict__ x2, const float* __restrict__ x3,
                             const float* __restrict__ h0, const float* __restrict__ h1,
                             const float* __restrict__ h2, const float* __restrict__ h3,
                             unsigned short* __restrict__ Ap) {
    const int idx = blockIdx.x * 256 + threadIdx.x;   // 4096*192 total (8 k each)
    const int m = idx / 192, k8 = idx % 192;
    const int g = m & 3, r = m >> 2;
    const float* src;
    if (k8 < 64) {
        const float* a = (g & 2) ? ((g & 1) ? x3 : x2) : ((g & 1) ? x1 : x0);
        src = a + (size_t)r * IN_C + k8 * 8;
    } else {
        const float* a = (g & 2) ? ((g & 1) ? h3 : h2) : ((g & 1) ? h1 : h0);
        src = a + (size_t)r * OUT_C + (k8 - 64) * 8;
    }
    float4 v0 = reinterpret_cast<const float4*>(src)[0];
    float4 v1 = reinterpret_cast<const float4*>(src)[1];
    ushort4 o0, o1;
    o0.x = f2bf(v0.x); o0.y = f2bf(v0.y); o0.z = f2bf(v0.z); o0.w = f2bf(v0.w);
    o1.x = f2bf(v1.x); o1.y = f2bf(v1.y); o1.z = f2bf(v1.z); o1.w = f2bf(v1.w);
    ushort4* dst = reinterpret_cast<ushort4*>(Ap + (size_t)m * KTOT + k8 * 8);
    dst[0] = o0; dst[1] = o1;
}

// ---- fused MDLSTM as one 256x256-tile GEMM, 8 waves, 16x16x32 MFMA.
// ONE barrier per K-tile: {4x(reads | stage | 16 MFMA)} free-running chunks,
// then vmcnt(0)+s_barrier. Staging writes only the nxt buffer; barrier
// crossing implies all waves consumed their reads -> single sync is safe.
__global__ __launch_bounds__(512, 2) void mdlstm_main(
    const unsigned short* __restrict__ Ap,    // [4096][1536] bf16
    const unsigned short* __restrict__ xT,    // [8192][512]  bf16
    const unsigned short* __restrict__ h0T,   // [8192][1024] bf16
    const unsigned short* __restrict__ h1T,   // [8192][1024] bf16
    const float* __restrict__ b_i, const float* __restrict__ b_f,
    const float* __restrict__ b_g, const float* __restrict__ b_o,
    const float* __restrict__ cp0, const float* __restrict__ cp1,
    const float* __restrict__ wsum,
    float* __restrict__ out)
{
    // 2 bufs x 64KB: A(half0)@0, A(half1)@16K, B(dir0)@32K, B(dir1)@48K
    // each 16KB region = [kk(2)][row(128)][64B], byte-swizzle ((row>>1)&3)<<4
    __shared__ __align__(16) unsigned char smem[131072];

    const int tid  = threadIdx.x;
    const int lane = tid & 63;
    const int wid  = tid >> 6;      // 0..7
    const int wm   = wid >> 2;      // 0..1 : A-half
    const int wn   = wid & 3;       // 0..3 : (dir = wn>>1, sample-half = wn&1)
    const int g4   = lane >> 4;
    const int l16  = lane & 15;

    const int by    = blockIdx.y;         // 0..15
    const int bcol  = blockIdx.x * 128;   // sample base
    const int browM = by * 256;           // A'-row base

    f32x4 acc[8][4];
#pragma unroll
    for (int mf = 0; mf < 8; ++mf)
#pragma unroll
        for (int nf = 0; nf < 4; ++nf)
            acc[mf][nf] = (f32x4){0.f, 0.f, 0.f, 0.f};

    auto stage_A = [&](int P, int hA, int j1) {
#pragma unroll
        for (int c = 0; c < 2; ++c) {
            const int u    = c * 8192 + tid * 16;
            const int rloc = (u >> 6) & 127;
            const int kb   = (u & 63) ^ (((u >> 7) & 3) << 4);
            const char* src = (const char*)Ap
                + ((size_t)(browM + hA * 128 + rloc) * KTOT + j1 * 64 + c * 32) * 2 + kb;
            __builtin_amdgcn_global_load_lds((const unsigned int*)src,
                (unsigned int*)(smem + P * 65536 + hA * 16384 + u), 16, 0, 0);
        }
    };
    auto stage_B = [&](int P, int d, int j2) {
#pragma unroll
        for (int c = 0; c < 2; ++c) {
            const int u    = c * 8192 + tid * 16;
            const int rloc = (u >> 6) & 127;
            const int kb   = (u & 63) ^ (((u >> 7) & 3) << 4);
            const char* src;
            if (j2 < 8) {   // x-region: both dirs read the same xT tile
                src = (const char*)xT + ((size_t)(bcol + rloc) * IN_C + j2 * 64 + c * 32) * 2 + kb;
            } else {
                const unsigned short* hsrc = d ? h1T : h0T;
                src = (const char*)hsrc + ((size_t)(bcol + rloc) * OUT_C + (j2 - 8) * 64 + c * 32) * 2 + kb;
            }
            __builtin_amdgcn_global_load_lds((const unsigned int*)src,
                (unsigned int*)(smem + P * 65536 + 32768 + d * 16384 + u), 16, 0, 0);
        }
    };

    auto swzb = [](int u) { return u ^ (((u >> 7) & 3) << 4); };
    auto fragA = [&](int P, int mf, int kk) -> bf16x8 {
        const int u = kk * 8192 + (mf * 16 + l16) * 64 + g4 * 16;
        return *reinterpret_cast<const bf16x8*>(smem + P * 65536 + wm * 16384 + swzb(u));
    };
    auto fragB = [&](int P, int nf, int kk) -> bf16x8 {
        const int u = kk * 8192 + ((wn & 1) * 64 + nf * 16 + l16) * 64 + g4 * 16;
        return *reinterpret_cast<const bf16x8*>(smem + P * 65536 + 32768 + (wn >> 1) * 16384 + swzb(u));
    };

    bf16x8 aF[2][2];   // [mi][kk] — current cluster's A pair
    bf16x8 bF[4][2];   // [nf][kk] — current tile's B frags (live whole tile)

    auto cluster = [&](int M) {
        __builtin_amdgcn_s_setprio(1);
#pragma unroll
        for (int kk = 0; kk < 2; ++kk)
#pragma unroll
            for (int mi = 0; mi < 2; ++mi)
#pragma unroll
                for (int nf = 0; nf < 4; ++nf)
                    acc[M + mi][nf] = __builtin_amdgcn_mfma_f32_16x16x32_bf16(
                        aF[mi][kk], bF[nf][kk], acc[M + mi][nf], 0, 0, 0);
        __builtin_amdgcn_s_setprio(0);
    };
    auto loadA = [&](int P, int mf) {
#pragma unroll
        for (int kk = 0; kk < 2; ++kk) { aF[0][kk] = fragA(P, mf, kk); aF[1][kk] = fragA(P, mf + 1, kk); }
    };
    auto loadB = [&](int P) {
#pragma unroll
        for (int nf = 0; nf < 4; ++nf)
#pragma unroll
            for (int kk = 0; kk < 2; ++kk) bF[nf][kk] = fragB(P, nf, kk);
    };

    // One K-tile, ONE barrier. 4 free-running chunks of {reads|stage|16 MFMA}.
    auto ktile = [&](int j, int P, int PN) {
        const bool st = (j < 23);
        // chunk 1: B frags (8) + A mf0,1 (4) ; MFMA mf0,1
        loadB(P);
        loadA(P, 0);
        cluster(0);
        // chunk 2: A mf2,3 ; stage A(j+1) ; MFMA mf2,3
        loadA(P, 2);
        if (st) { stage_A(PN, 0, j + 1); stage_A(PN, 1, j + 1); }
        cluster(2);
        // chunk 3: A mf4,5 ; stage B(j+1) ; MFMA mf4,5
        loadA(P, 4);
        if (st) { stage_B(PN, 0, j + 1); stage_B(PN, 1, j + 1); }
        cluster(4);
        // chunk 4: A mf6,7 ; MFMA mf6,7 ; drain staged loads ; barrier
        loadA(P, 6);
        cluster(6);
        SFENCE(); VM0(); SFENCE();
        SBAR();
    };

    // ---------------- prologue: stage tile 0 ----------------
    stage_A(0, 0, 0); stage_A(0, 1, 0);
    stage_B(0, 0, 0); stage_B(0, 1, 0);
    SFENCE(); VM0(); SFENCE();
    SBAR();

    // ---------------- main loop: 24 K-tiles ----------------
#pragma unroll 1
    for (int jj = 0; jj < 12; ++jj) {
        ktile(2 * jj,     0, 1);
        ktile(2 * jj + 1, 1, 0);
    }

    // ---------------- epilogue: lane-local gates; LDS exchange for dir combine ----
    const float w0 = wsum[0], w1 = wsum[1];
    const int   d  = wn >> 1;
    const float* cp = d ? cp1 : cp0;
    const float wd  = d ? w1 : w0;

    float rc[8][4], rh[8][4];
#pragma unroll
    for (int mf = 0; mf < 8; ++mf) {
        const int orow = by * 64 + wm * 32 + mf * 4 + g4;
        const float bi = b_i[orow], bff = b_f[orow], bg = b_g[orow], bo = b_o[orow];
#pragma unroll
        for (int nf = 0; nf < 4; ++nf) {
            const int scol = bcol + (wn & 1) * 64 + nf * 16 + l16;
            float i_ = sigmoid_f(acc[mf][nf][0] + bi);
            float f_ = sigmoid_f(acc[mf][nf][1] + bff);
            float g_ = tanh_f  (acc[mf][nf][2] + bg);
            float o_ = sigmoid_f(acc[mf][nf][3] + bo);
            float cc = f_ * cp[(size_t)orow * NSAMP + scol] + i_ * g_;
            float hh = o_ * tanh_f(cc);
            rc[mf][nf] = wd * cc;
            rh[mf][nf] = wd * hh;
        }
    }

    float* ex = (float*)smem;
    const int rbase = (wm * 2 + (wn & 1)) * 4096;   // 16KB region per (wm, sample-half)
    if (d == 1) {
#pragma unroll
        for (int mf = 0; mf < 8; ++mf)
#pragma unroll
            for (int nf = 0; nf < 4; ++nf) {
                const int slot = rbase + (mf * 4 + nf) * 64 + lane;
                ex[slot]        = rc[mf][nf];
                ex[slot + 2048] = rh[mf][nf];
            }
    }
    SBAR();
    if (d == 0) {
#pragma unroll
        for (int mf = 0; mf < 8; ++mf) {
            const int orow = by * 64 + wm * 32 + mf * 4 + g4;
#pragma unroll
            for (int nf = 0; nf < 4; ++nf) {
                const int scol = bcol + (wn & 1) * 64 + nf * 16 + l16;
                const int slot = rbase + (mf * 4 + nf) * 64 + lane;
                out[(size_t)orow * NSAMP + scol] = rc[mf][nf] + ex[slot];
                out[(size_t)OUT_C * NSAMP + (size_t)orow * NSAMP + scol] = rh[mf][nf] + ex[slot + 2048];
            }
        }
    }
}

extern "C" void kernel_launch(void* const* d_in, const int* in_sizes, int n_in,
                              void* d_out, int out_size, void* d_ws, size_t ws_size,
                              hipStream_t stream) {
    (void)in_sizes; (void)n_in; (void)out_size; (void)ws_size;

    const float* x    = (const float*)d_in[0];
    const float* cp0  = (const float*)d_in[1];
    const float* hp0  = (const float*)d_in[2];
    const float* cp1  = (const float*)d_in[3];
    const float* hp1  = (const float*)d_in[4];
    const float* b_i  = (const float*)d_in[13];
    const float* b_f  = (const float*)d_in[14];
    const float* b_g  = (const float*)d_in[15];
    const float* b_o  = (const float*)d_in[16];
    const float* wsum = (const float*)d_in[17];
    float* out = (float*)d_out;

    // workspace: xT 8MB @0, h0T 16MB @8M, h1T 16MB @24M, Ap 12MB @40M
    char* ws = (char*)d_ws;
    unsigned short* xT  = (unsigned short*)(ws);
    unsigned short* h0T = (unsigned short*)(ws + (size_t)8  * 1024 * 1024);
    unsigned short* h1T = (unsigned short*)(ws + (size_t)24 * 1024 * 1024);
    unsigned short* Ap  = (unsigned short*)(ws + (size_t)40 * 1024 * 1024);

    dim3 tb(32, 8);
    tcvt_kernel<<<dim3(NSAMP / 32, IN_C  / 32), tb, 0, stream>>>(x,   xT,  IN_C,  NSAMP);
    tcvt_kernel<<<dim3(NSAMP / 32, OUT_C / 32), tb, 0, stream>>>(hp0, h0T, OUT_C, NSAMP);
    tcvt_kernel<<<dim3(NSAMP / 32, OUT_C / 32), tb, 0, stream>>>(hp1, h1T, OUT_C, NSAMP);

    packA_kernel<<<(4096 * 192) / 256, 256, 0, stream>>>(
        (const float*)d_in[5], (const float*)d_in[6], (const float*)d_in[7], (const float*)d_in[8],
        (const float*)d_in[9], (const float*)d_in[10], (const float*)d_in[11], (const float*)d_in[12],
        Ap);

    mdlstm_main<<<dim3(NSAMP / 128, OUT_C / 64), 512, 0, stream>>>(
        Ap, xT, h0T, h1T, b_i, b_f, b_g, b_o, cp0, cp1, wsum, out);
}